// Round 18
// baseline (104.925 us; speedup 1.0000x reference)
//
#include <hip/hip_runtime.h>

#define N_NODES 50000
#define N_PAD   50176      // 196 * 256
#define F_IN 256
#define HID 128
#define CLS 32
#define N_EDGE 800000

#define NB    196          // edge chunks / blocks for multisplit
#define NPART 196          // partitions of 256 nodes
#define CHUNK 4082         // ceil(800000/196)
#define GBLKS 782          // ceil(50000/64) gemm1 blocks (64 rows each)

typedef short bf16x8 __attribute__((ext_vector_type(8)));
typedef short s16x4  __attribute__((ext_vector_type(4)));
typedef short s16x8  __attribute__((ext_vector_type(8)));
typedef float f32x2  __attribute__((ext_vector_type(2)));
typedef float f32x4  __attribute__((ext_vector_type(4)));

static __device__ inline short f2bf(float f) {
    union { float f; unsigned u; } v; v.f = f;
    unsigned r = v.u + 0x7FFFu + ((v.u >> 16) & 1u);
    return (short)(r >> 16);
}

static __device__ inline unsigned char f2fp8(float f) {
    return (unsigned char)(__builtin_amdgcn_cvt_pk_fp8_f32(f, f, 0, false) & 0xFF);
}

// ================= kernel 1: histA + W1/W2 convert to FRAGMENT-PACKED layout =========

__global__ __launch_bounds__(256) void k_pre(const int* __restrict__ dst,
                                             int* __restrict__ counts,
                                             const float* __restrict__ W1,
                                             short* __restrict__ WtP,
                                             const float* __restrict__ W2,
                                             short* __restrict__ Wt2P) {
    int blk = blockIdx.x, tid = threadIdx.x;
    if (blk < NB) {
        __shared__ int hist[NPART];
        if (tid < NPART) hist[tid] = 0;
        __syncthreads();
        int lo = blk * CHUNK, hi = min(lo + CHUNK, N_EDGE);
        for (int e = lo + tid; e < hi; e += 256)
            atomicAdd(&hist[dst[e] >> 8], 1);
        __syncthreads();
        if (tid < NPART) counts[blk * NPART + tid] = hist[tid];
    } else if (blk < NB + 128) {
        int idx = (blk - NB) * 256 + tid;        // 0..32767
        int e  = idx & 7;
        int l  = (idx >> 3) & 63;
        int nt = (idx >> 9) & 7;
        int ks = idx >> 12;                      // 0..7
        int k  = ks * 32 + ((l >> 4) * 8) + e;
        int col = nt * 16 + (l & 15);
        WtP[idx] = f2bf(W1[(size_t)k * HID + col]);
    } else {
        int idx = (blk - NB - 128) * 256 + tid;  // 0..4095
        int e  = idx & 7;
        int l  = (idx >> 3) & 63;
        int nt = (idx >> 9) & 1;
        int ks = (idx >> 10) & 3;                // 0..3
        int k  = ks * 32 + ((l >> 4) * 8) + e;
        int col = nt * 16 + (l & 15);
        Wt2P[idx] = f2bf(W2[(size_t)k * CLS + col]);
    }
}

// ================= kernel 2: bucket (computes own base + partbase from counts) =======

__global__ __launch_bounds__(256) void k_bucket(const int* __restrict__ src,
                                                const int* __restrict__ dst,
                                                const int* __restrict__ counts,
                                                int* __restrict__ bucket) {
    __shared__ int s[256];
    __shared__ int cur[NPART];
    int tid = threadIdx.x, blk = blockIdx.x;

    int pre = 0, tot = 0;
    if (tid < NPART) {
#pragma unroll 4
        for (int b = 0; b < NB; ++b) {
            int c = counts[b * NPART + tid];     // coalesced across threads
            tot += c;
            if (b < blk) pre += c;
        }
    }
    s[tid] = (tid < NPART) ? tot : 0;
    __syncthreads();
#pragma unroll
    for (int off = 1; off < 256; off <<= 1) {
        int t = (tid >= off) ? s[tid - off] : 0;
        __syncthreads();
        s[tid] += t;
        __syncthreads();
    }
    if (tid < NPART) cur[tid] = (s[tid] - tot) + pre;    // partbase[p] + local prefix
    __syncthreads();
    int lo = blk * CHUNK, hi = min(lo + CHUNK, N_EDGE);
    for (int e = lo + tid; e < hi; e += 256) {
        int d = dst[e], sv = src[e];
        int pos = atomicAdd(&cur[d >> 8], 1);
        bucket[pos] = ((d & 255) << 16) | sv;
    }
}

// ================= kernel 3: csr_final (blocks 0..195) ∥ GEMM1-LDS (196..977) ========

__global__ __launch_bounds__(256) void k_csrf_gemm1(const int* __restrict__ bucket,
                                                    const int* __restrict__ counts,
                                                    int* __restrict__ esrc,
                                                    int* __restrict__ offs,
                                                    float* __restrict__ dinv,
                                                    const float* __restrict__ x,
                                                    const short* __restrict__ WtP,
                                                    unsigned char* __restrict__ h) {
    __shared__ short tile[64][256];   // 32 KB; aliased by csr_final branch
    int blk = blockIdx.x, tid = threadIdx.x;

    if (blk < NPART) {
        // ---- csr_final (aliases tile memory) ----
        int* sA = (int*)&tile[0][0];
        int* sB = sA + 256;
        int* sC = sB + 256;
        int* sX = sC + 256;
        int p = blk;
        int tot = 0;
        if (tid < NPART) {
#pragma unroll 4
            for (int b = 0; b < NB; ++b) tot += counts[b * NPART + tid];
        }
        sA[tid] = (tid < NPART) ? tot : 0;
        __syncthreads();
#pragma unroll
        for (int off = 1; off < 256; off <<= 1) {
            int t = (tid >= off) ? sA[tid - off] : 0;
            __syncthreads();
            sA[tid] += t;
            __syncthreads();
        }
        if (tid == p) { sX[0] = sA[tid] - tot; sX[1] = tot; }
        sB[tid] = 0;
        __syncthreads();
        int beg = sX[0], end = beg + sX[1];
        for (int i = beg + tid; i < end; i += 256)
            atomicAdd(&sB[bucket[i] >> 16], 1);
        __syncthreads();
        int hv = sB[tid];
        sA[tid] = hv;
        __syncthreads();
#pragma unroll
        for (int off = 1; off < 256; off <<= 1) {
            int t = (tid >= off) ? sA[tid - off] : 0;
            __syncthreads();
            sA[tid] += t;
            __syncthreads();
        }
        int excl = sA[tid] - hv;
        sC[tid] = excl;
        int node = p * 256 + tid;
        if (node <= N_NODES) offs[node] = beg + excl;
        if (node < N_NODES) dinv[node] = rsqrtf((float)(hv + 1));
        __syncthreads();
        for (int i = beg + tid; i < end; i += 256) {
            int pk = bucket[i];
            int slot = atomicAdd(&sC[pk >> 16], 1);
            esrc[beg + slot] = pk & 0xFFFF;
        }
        return;
    }

    // ---- GEMM1: stage x tile (64 rows) into LDS as bf16, then MFMA with packed B ----
    const int R0 = (blk - NPART) * 64;

#pragma unroll 8
    for (int it = 0; it < 16; ++it) {
        int rl = it * 4 + (tid >> 6);
        int row = min(R0 + rl, N_NODES - 1);
        int c = (tid & 63) * 4;
        f32x4 xv = *(const f32x4*)(x + (size_t)row * F_IN + c);
        s16x4 bv = { f2bf(xv[0]), f2bf(xv[1]), f2bf(xv[2]), f2bf(xv[3]) };
        int byte = rl * 512 + c * 2;
        byte ^= ((rl & 7) << 4);          // swizzle (write side)
        *(s16x4*)((char*)&tile[0][0] + byte) = bv;
    }
    __syncthreads();

    const int lane = tid & 63;
    const int w    = tid >> 6;
    const int l15  = lane & 15;
    const int lk   = lane >> 4;           // 0..3

    f32x4 acc[8] = {};

#pragma unroll
    for (int ks = 0; ks < F_IN / 32; ++ks) {
        const int kbase = ks * 32 + lk * 8;

        int rl = w * 16 + l15;
        int byte = rl * 512 + kbase * 2;
        byte ^= ((rl & 7) << 4);          // swizzle (read side)
        bf16x8 afrag = *(const bf16x8*)((char*)&tile[0][0] + byte);

        bf16x8 bfrag[8];
#pragma unroll
        for (int nt = 0; nt < 8; ++nt)
            bfrag[nt] = *(const bf16x8*)(WtP + (size_t)((ks * 8 + nt) * 64 + lane) * 8);

#pragma unroll
        for (int nt = 0; nt < 8; ++nt)
            acc[nt] = __builtin_amdgcn_mfma_f32_16x16x32_bf16(afrag, bfrag[nt], acc[nt], 0, 0, 0);
    }

#pragma unroll
    for (int r = 0; r < 4; ++r) {
        int m = R0 + w * 16 + lk * 4 + r;
        if (m < N_NODES) {
#pragma unroll
            for (int nt = 0; nt < 8; ++nt) {
                int n = nt * 16 + l15;
                h[(size_t)m * HID + n] = f2fp8(acc[nt][r]);
            }
        }
    }
}

// ================= kernel 4: fused gather1 + GEMM2 =================
// Block = 16 nodes (3125*16 = 50000). Gather into LDS [16][132] bf16; wave 0
// then computes h2[16][32] = relu(a1) @ W2 via 8 MFMAs (packed Wt2P).

#define ALDS2 132

__global__ __launch_bounds__(256) void k_g1g2(const int* __restrict__ offs,
                                              const int* __restrict__ esrc,
                                              const unsigned char* __restrict__ h,
                                              const float* __restrict__ dinv,
                                              const float* __restrict__ b,
                                              const short* __restrict__ Wt2P,
                                              unsigned char* __restrict__ h2) {
    __shared__ short a_lds[16][ALDS2];
    const int tid = threadIdx.x;
    const int nl = tid >> 4;                 // local node 0..15
    const int node = blockIdx.x * 16 + nl;   // always < N_NODES
    const int lane16 = tid & 15;
    const int f = lane16 * 8;

    float dv = dinv[node];
    uint2 hv = *(const uint2*)(h + (size_t)node * HID + f);
    f32x2 q0 = __builtin_amdgcn_cvt_pk_f32_fp8(hv.x, false);
    f32x2 q1 = __builtin_amdgcn_cvt_pk_f32_fp8(hv.x, true);
    f32x2 q2 = __builtin_amdgcn_cvt_pk_f32_fp8(hv.y, false);
    f32x2 q3 = __builtin_amdgcn_cvt_pk_f32_fp8(hv.y, true);
    float self = dv * dv;
    float a0 = q0[0] * self, a1 = q0[1] * self, a2 = q1[0] * self, a3 = q1[1] * self;
    float a4 = q2[0] * self, a5 = q2[1] * self, a6 = q3[0] * self, a7 = q3[1] * self;

    int beg = offs[node], end = offs[node + 1];
    int p = beg;
#define ACC8(vv, nn) { \
    f32x2 c0 = __builtin_amdgcn_cvt_pk_f32_fp8(vv.x, false); \
    f32x2 c1 = __builtin_amdgcn_cvt_pk_f32_fp8(vv.x, true);  \
    f32x2 c2 = __builtin_amdgcn_cvt_pk_f32_fp8(vv.y, false); \
    f32x2 c3 = __builtin_amdgcn_cvt_pk_f32_fp8(vv.y, true);  \
    a0 += c0[0] * nn; a1 += c0[1] * nn; a2 += c1[0] * nn; a3 += c1[1] * nn; \
    a4 += c2[0] * nn; a5 += c2[1] * nn; a6 += c3[0] * nn; a7 += c3[1] * nn; }
    for (; p + 7 < end; p += 8) {
        int s0 = esrc[p + 0], s1 = esrc[p + 1], s2 = esrc[p + 2], s3 = esrc[p + 3];
        int s4 = esrc[p + 4], s5 = esrc[p + 5], s6 = esrc[p + 6], s7 = esrc[p + 7];
        float n0 = dinv[s0] * dv, n1 = dinv[s1] * dv, n2 = dinv[s2] * dv, n3 = dinv[s3] * dv;
        float n4 = dinv[s4] * dv, n5 = dinv[s5] * dv, n6 = dinv[s6] * dv, n7 = dinv[s7] * dv;
        uint2 v0 = *(const uint2*)(h + (size_t)s0 * HID + f);
        uint2 v1 = *(const uint2*)(h + (size_t)s1 * HID + f);
        uint2 v2 = *(const uint2*)(h + (size_t)s2 * HID + f);
        uint2 v3 = *(const uint2*)(h + (size_t)s3 * HID + f);
        uint2 v4 = *(const uint2*)(h + (size_t)s4 * HID + f);
        uint2 v5 = *(const uint2*)(h + (size_t)s5 * HID + f);
        uint2 v6 = *(const uint2*)(h + (size_t)s6 * HID + f);
        uint2 v7 = *(const uint2*)(h + (size_t)s7 * HID + f);
        ACC8(v0, n0); ACC8(v1, n1); ACC8(v2, n2); ACC8(v3, n3);
        ACC8(v4, n4); ACC8(v5, n5); ACC8(v6, n6); ACC8(v7, n7);
    }
    for (; p + 3 < end; p += 4) {
        int s0 = esrc[p + 0], s1 = esrc[p + 1], s2 = esrc[p + 2], s3 = esrc[p + 3];
        float n0 = dinv[s0] * dv, n1 = dinv[s1] * dv, n2 = dinv[s2] * dv, n3 = dinv[s3] * dv;
        uint2 v0 = *(const uint2*)(h + (size_t)s0 * HID + f);
        uint2 v1 = *(const uint2*)(h + (size_t)s1 * HID + f);
        uint2 v2 = *(const uint2*)(h + (size_t)s2 * HID + f);
        uint2 v3 = *(const uint2*)(h + (size_t)s3 * HID + f);
        ACC8(v0, n0); ACC8(v1, n1); ACC8(v2, n2); ACC8(v3, n3);
    }
    for (; p < end; ++p) {
        int s = esrc[p];
        float nrm = dinv[s] * dv;
        uint2 v = *(const uint2*)(h + (size_t)s * HID + f);
        ACC8(v, nrm);
    }
    float4 bv0 = *(const float4*)(b + f);
    float4 bv1 = *(const float4*)(b + f + 4);
    s16x8 o = { f2bf(a0 + bv0.x), f2bf(a1 + bv0.y), f2bf(a2 + bv0.z), f2bf(a3 + bv0.w),
                f2bf(a4 + bv1.x), f2bf(a5 + bv1.y), f2bf(a6 + bv1.z), f2bf(a7 + bv1.w) };
    *(s16x8*)&a_lds[nl][f] = o;
    __syncthreads();

    // ---- GEMM2 tail on wave 0 ----
    if (tid < 64) {
        const int lane = tid;
        const int l15 = lane & 15;
        const int lk  = lane >> 4;
        f32x4 acc[2] = {};
#pragma unroll
        for (int ks = 0; ks < HID / 32; ++ks) {
            const int kbase = ks * 32 + lk * 8;
            bf16x8 av = *(const bf16x8*)&a_lds[l15][kbase];
#pragma unroll
            for (int e = 0; e < 8; ++e) if (av[e] < 0) av[e] = 0;   // bf16 relu
#pragma unroll
            for (int nt = 0; nt < 2; ++nt) {
                bf16x8 bfrag = *(const bf16x8*)(Wt2P + (size_t)((ks * 2 + nt) * 64 + lane) * 8);
                acc[nt] = __builtin_amdgcn_mfma_f32_16x16x32_bf16(av, bfrag, acc[nt], 0, 0, 0);
            }
        }
#pragma unroll
        for (int r = 0; r < 4; ++r) {
            int m = blockIdx.x * 16 + lk * 4 + r;
#pragma unroll
            for (int nt = 0; nt < 2; ++nt) {
                int n = nt * 16 + l15;
                h2[(size_t)m * CLS + n] = f2fp8(acc[nt][r]);
            }
        }
    }
}

// ================= kernel 5: gather2 (fp8 in, 4 lanes x uint2) + log-softmax =========

__global__ __launch_bounds__(256) void k_gather2(const int* __restrict__ offs,
                                                 const int* __restrict__ esrc,
                                                 const unsigned char* __restrict__ h,
                                                 const float* __restrict__ dinv,
                                                 const float* __restrict__ b,
                                                 float* __restrict__ out) {
    int node = blockIdx.x * 64 + (threadIdx.x >> 2);
    int sub = threadIdx.x & 3;
    if (node >= N_NODES) return;
    int f = sub * 8;
    float dv = dinv[node];
    uint2 hv = *(const uint2*)(h + (size_t)node * CLS + f);
    f32x2 q0 = __builtin_amdgcn_cvt_pk_f32_fp8(hv.x, false);
    f32x2 q1 = __builtin_amdgcn_cvt_pk_f32_fp8(hv.x, true);
    f32x2 q2 = __builtin_amdgcn_cvt_pk_f32_fp8(hv.y, false);
    f32x2 q3 = __builtin_amdgcn_cvt_pk_f32_fp8(hv.y, true);
    float self = dv * dv;
    float a0 = q0[0] * self, a1 = q0[1] * self, a2 = q1[0] * self, a3 = q1[1] * self;
    float a4 = q2[0] * self, a5 = q2[1] * self, a6 = q3[0] * self, a7 = q3[1] * self;

    int beg = offs[node], end = offs[node + 1];
    int p = beg;
    for (; p + 7 < end; p += 8) {
        int s0 = esrc[p + 0], s1 = esrc[p + 1], s2 = esrc[p + 2], s3 = esrc[p + 3];
        int s4 = esrc[p + 4], s5 = esrc[p + 5], s6 = esrc[p + 6], s7 = esrc[p + 7];
        float n0 = dinv[s0] * dv, n1 = dinv[s1] * dv, n2 = dinv[s2] * dv, n3 = dinv[s3] * dv;
        float n4 = dinv[s4] * dv, n5 = dinv[s5] * dv, n6 = dinv[s6] * dv, n7 = dinv[s7] * dv;
        uint2 v0 = *(const uint2*)(h + (size_t)s0 * CLS + f);
        uint2 v1 = *(const uint2*)(h + (size_t)s1 * CLS + f);
        uint2 v2 = *(const uint2*)(h + (size_t)s2 * CLS + f);
        uint2 v3 = *(const uint2*)(h + (size_t)s3 * CLS + f);
        uint2 v4 = *(const uint2*)(h + (size_t)s4 * CLS + f);
        uint2 v5 = *(const uint2*)(h + (size_t)s5 * CLS + f);
        uint2 v6 = *(const uint2*)(h + (size_t)s6 * CLS + f);
        uint2 v7 = *(const uint2*)(h + (size_t)s7 * CLS + f);
        ACC8(v0, n0); ACC8(v1, n1); ACC8(v2, n2); ACC8(v3, n3);
        ACC8(v4, n4); ACC8(v5, n5); ACC8(v6, n6); ACC8(v7, n7);
    }
    for (; p + 3 < end; p += 4) {
        int s0 = esrc[p + 0], s1 = esrc[p + 1], s2 = esrc[p + 2], s3 = esrc[p + 3];
        float n0 = dinv[s0] * dv, n1 = dinv[s1] * dv, n2 = dinv[s2] * dv, n3 = dinv[s3] * dv;
        uint2 v0 = *(const uint2*)(h + (size_t)s0 * CLS + f);
        uint2 v1 = *(const uint2*)(h + (size_t)s1 * CLS + f);
        uint2 v2 = *(const uint2*)(h + (size_t)s2 * CLS + f);
        uint2 v3 = *(const uint2*)(h + (size_t)s3 * CLS + f);
        ACC8(v0, n0); ACC8(v1, n1); ACC8(v2, n2); ACC8(v3, n3);
    }
    for (; p < end; ++p) {
        int s = esrc[p];
        float nrm = dinv[s] * dv;
        uint2 v = *(const uint2*)(h + (size_t)s * CLS + f);
        ACC8(v, nrm);
    }
#undef ACC8
    float4 bv0 = *(const float4*)(b + f);
    float4 bv1 = *(const float4*)(b + f + 4);
    a0 += bv0.x; a1 += bv0.y; a2 += bv0.z; a3 += bv0.w;
    a4 += bv1.x; a5 += bv1.y; a6 += bv1.z; a7 += bv1.w;

    // log-softmax across 4-lane group (32 values = 8 local x 4 lanes)
    float m = fmaxf(fmaxf(fmaxf(a0, a1), fmaxf(a2, a3)),
                    fmaxf(fmaxf(a4, a5), fmaxf(a6, a7)));
    m = fmaxf(m, __shfl_xor(m, 1, 4));
    m = fmaxf(m, __shfl_xor(m, 2, 4));
    float sum = expf(a0 - m) + expf(a1 - m) + expf(a2 - m) + expf(a3 - m)
              + expf(a4 - m) + expf(a5 - m) + expf(a6 - m) + expf(a7 - m);
    sum += __shfl_xor(sum, 1, 4);
    sum += __shfl_xor(sum, 2, 4);
    float l = m + logf(sum);
    float4 o0 = { a0 - l, a1 - l, a2 - l, a3 - l };
    float4 o1 = { a4 - l, a5 - l, a6 - l, a7 - l };
    *(float4*)(out + (size_t)node * CLS + f)     = o0;
    *(float4*)(out + (size_t)node * CLS + f + 4) = o1;
}

// ================= launch =================

extern "C" void kernel_launch(void* const* d_in, const int* in_sizes, int n_in,
                              void* d_out, int out_size, void* d_ws, size_t ws_size,
                              hipStream_t stream) {
    const float* x  = (const float*)d_in[0];
    const int*   ei = (const int*)d_in[1];
    const float* W1 = (const float*)d_in[2];
    const float* b1 = (const float*)d_in[3];
    const float* W2 = (const float*)d_in[4];
    const float* b2 = (const float*)d_in[5];
    float* out = (float*)d_out;

    const int* src = ei;
    const int* dst = ei + N_EDGE;

    int* counts   = (int*)d_ws;                           // NB*NPART
    int* bucket   = counts + NB * NPART;                  // N_EDGE
    int* offs     = bucket + N_EDGE;                      // N_PAD
    int* esrc     = offs + N_PAD;                         // N_EDGE
    float* dinv   = (float*)(esrc + N_EDGE);              // N_PAD
    unsigned char* h1 = (unsigned char*)(dinv + N_PAD);   // N*HID fp8
    unsigned char* h2 = h1 + (size_t)N_NODES * HID;       // N*CLS fp8
    short* WtP    = (short*)(h2 + (size_t)N_NODES * CLS); // 32768 bf16 packed
    short* Wt2P   = WtP + HID * F_IN;                     // 4096 bf16 packed

    k_pre       <<<NB + 128 + 16, 256, 0, stream>>>(dst, counts, W1, WtP, W2, Wt2P);
    k_bucket    <<<NB,            256, 0, stream>>>(src, dst, counts, bucket);
    k_csrf_gemm1<<<NPART + GBLKS, 256, 0, stream>>>(bucket, counts, esrc, offs, dinv, x, WtP, h1);
    k_g1g2      <<<3125,          256, 0, stream>>>(offs, esrc, h1, dinv, b1, Wt2P, h2);
    k_gather2   <<<782,           256, 0, stream>>>(offs, esrc, h2, dinv, b2, out);
}

// Round 19
// 76.635 us; speedup vs baseline: 1.3692x; 1.3692x over previous
//
#include <hip/hip_runtime.h>

#define N_NODES 50000
#define N_PAD   50176      // 196 * 256
#define F_IN 256
#define HID 128
#define CLS 32
#define N_EDGE 800000

#define NB    196          // edge chunks / blocks for multisplit
#define NPART 196          // partitions of 256 nodes
#define CHUNK 4082         // ceil(800000/196)
#define GBLKS 782          // ceil(50000/64) gemm1 blocks (64 rows each)

typedef short bf16x8 __attribute__((ext_vector_type(8)));
typedef short s16x4  __attribute__((ext_vector_type(4)));
typedef short s16x8  __attribute__((ext_vector_type(8)));
typedef float f32x2  __attribute__((ext_vector_type(2)));
typedef float f32x4  __attribute__((ext_vector_type(4)));

static __device__ inline short f2bf(float f) {
    union { float f; unsigned u; } v; v.f = f;
    unsigned r = v.u + 0x7FFFu + ((v.u >> 16) & 1u);
    return (short)(r >> 16);
}

static __device__ inline unsigned char f2fp8(float f) {
    return (unsigned char)(__builtin_amdgcn_cvt_pk_fp8_f32(f, f, 0, false) & 0xFF);
}

// ================= kernel 1: histA + W1/W2 convert to FRAGMENT-PACKED layout =========

__global__ __launch_bounds__(256) void k_pre(const int* __restrict__ dst,
                                             int* __restrict__ counts,
                                             const float* __restrict__ W1,
                                             short* __restrict__ WtP,
                                             const float* __restrict__ W2,
                                             short* __restrict__ Wt2P) {
    int blk = blockIdx.x, tid = threadIdx.x;
    if (blk < NB) {
        __shared__ int hist[NPART];
        if (tid < NPART) hist[tid] = 0;
        __syncthreads();
        int lo = blk * CHUNK, hi = min(lo + CHUNK, N_EDGE);
        for (int e = lo + tid; e < hi; e += 256)
            atomicAdd(&hist[dst[e] >> 8], 1);
        __syncthreads();
        if (tid < NPART) counts[blk * NPART + tid] = hist[tid];
    } else if (blk < NB + 128) {
        int idx = (blk - NB) * 256 + tid;        // 0..32767
        int e  = idx & 7;
        int l  = (idx >> 3) & 63;
        int nt = (idx >> 9) & 7;
        int ks = idx >> 12;                      // 0..7
        int k  = ks * 32 + ((l >> 4) * 8) + e;
        int col = nt * 16 + (l & 15);
        WtP[idx] = f2bf(W1[(size_t)k * HID + col]);
    } else {
        int idx = (blk - NB - 128) * 256 + tid;  // 0..4095
        int e  = idx & 7;
        int l  = (idx >> 3) & 63;
        int nt = (idx >> 9) & 1;
        int ks = (idx >> 10) & 3;                // 0..3
        int k  = ks * 32 + ((l >> 4) * 8) + e;
        int col = nt * 16 + (l & 15);
        Wt2P[idx] = f2bf(W2[(size_t)k * CLS + col]);
    }
}

// ================= kernel 2: scanP1 =================

__global__ __launch_bounds__(256) void k_scanP1(const int* __restrict__ counts,
                                                int* __restrict__ base,
                                                int* __restrict__ ptot) {
    __shared__ int s[256];
    int tid = threadIdx.x, p = blockIdx.x;
    int v = (tid < NB) ? counts[tid * NPART + p] : 0;
    s[tid] = v;
    __syncthreads();
#pragma unroll
    for (int off = 1; off < 256; off <<= 1) {
        int t = (tid >= off) ? s[tid - off] : 0;
        __syncthreads();
        s[tid] += t;
        __syncthreads();
    }
    if (tid < NB) base[tid * NPART + p] = s[tid] - v;   // local exclusive
    if (tid == 255) ptot[p] = s[255];
}

// ================= kernel 3: bucket (computes partbase locally from ptot) ============

__global__ __launch_bounds__(256) void k_bucket(const int* __restrict__ src,
                                                const int* __restrict__ dst,
                                                const int* __restrict__ base,
                                                const int* __restrict__ ptot,
                                                int* __restrict__ bucket) {
    __shared__ int s[256];
    __shared__ int cur[NPART];
    int tid = threadIdx.x, blk = blockIdx.x;
    int v = (tid < NPART) ? ptot[tid] : 0;
    s[tid] = v;
    __syncthreads();
#pragma unroll
    for (int off = 1; off < 256; off <<= 1) {
        int t = (tid >= off) ? s[tid - off] : 0;
        __syncthreads();
        s[tid] += t;
        __syncthreads();
    }
    if (tid < NPART) cur[tid] = base[blk * NPART + tid] + (s[tid] - v);
    __syncthreads();
    int lo = blk * CHUNK, hi = min(lo + CHUNK, N_EDGE);
    for (int e = lo + tid; e < hi; e += 256) {
        int d = dst[e], sv = src[e];
        int pos = atomicAdd(&cur[d >> 8], 1);
        bucket[pos] = ((d & 255) << 16) | sv;
    }
}

// ================= kernel 4: csr_final (blocks 0..195) ∥ GEMM1-LDS (196..977) ========

__global__ __launch_bounds__(256) void k_csrf_gemm1(const int* __restrict__ bucket,
                                                    const int* __restrict__ ptot,
                                                    int* __restrict__ esrc,
                                                    int* __restrict__ offs,
                                                    float* __restrict__ dinv,
                                                    const float* __restrict__ x,
                                                    const short* __restrict__ WtP,
                                                    unsigned char* __restrict__ h) {
    __shared__ short tile[64][256];   // 32 KB; aliased by csr_final branch
    int blk = blockIdx.x, tid = threadIdx.x;

    if (blk < NPART) {
        // ---- csr_final (aliases tile memory) ----
        int* sA = (int*)&tile[0][0];
        int* sB = sA + 256;
        int* sC = sB + 256;
        int* sX = sC + 256;
        int p = blk;
        int v = (tid < NPART) ? ptot[tid] : 0;
        sA[tid] = v;
        __syncthreads();
#pragma unroll
        for (int off = 1; off < 256; off <<= 1) {
            int t = (tid >= off) ? sA[tid - off] : 0;
            __syncthreads();
            sA[tid] += t;
            __syncthreads();
        }
        if (tid == p) sX[0] = sA[tid] - v;
        sB[tid] = 0;
        __syncthreads();
        int beg = sX[0], end = beg + ptot[p];
        for (int i = beg + tid; i < end; i += 256)
            atomicAdd(&sB[bucket[i] >> 16], 1);
        __syncthreads();
        int hv = sB[tid];
        sA[tid] = hv;
        __syncthreads();
#pragma unroll
        for (int off = 1; off < 256; off <<= 1) {
            int t = (tid >= off) ? sA[tid - off] : 0;
            __syncthreads();
            sA[tid] += t;
            __syncthreads();
        }
        int excl = sA[tid] - hv;
        sC[tid] = excl;
        int node = p * 256 + tid;
        if (node <= N_NODES) offs[node] = beg + excl;
        if (node < N_NODES) dinv[node] = rsqrtf((float)(hv + 1));
        __syncthreads();
        for (int i = beg + tid; i < end; i += 256) {
            int pk = bucket[i];
            int slot = atomicAdd(&sC[pk >> 16], 1);
            esrc[beg + slot] = pk & 0xFFFF;
        }
        return;
    }

    // ---- GEMM1: stage x tile (64 rows) into LDS as bf16, then MFMA with packed B ----
    const int R0 = (blk - NPART) * 64;

#pragma unroll 8
    for (int it = 0; it < 16; ++it) {
        int rl = it * 4 + (tid >> 6);
        int row = min(R0 + rl, N_NODES - 1);
        int c = (tid & 63) * 4;
        f32x4 xv = *(const f32x4*)(x + (size_t)row * F_IN + c);
        s16x4 bv = { f2bf(xv[0]), f2bf(xv[1]), f2bf(xv[2]), f2bf(xv[3]) };
        int byte = rl * 512 + c * 2;
        byte ^= ((rl & 7) << 4);          // swizzle (write side)
        *(s16x4*)((char*)&tile[0][0] + byte) = bv;
    }
    __syncthreads();

    const int lane = tid & 63;
    const int w    = tid >> 6;
    const int l15  = lane & 15;
    const int lk   = lane >> 4;           // 0..3

    f32x4 acc[8] = {};

#pragma unroll
    for (int ks = 0; ks < F_IN / 32; ++ks) {
        const int kbase = ks * 32 + lk * 8;

        int rl = w * 16 + l15;
        int byte = rl * 512 + kbase * 2;
        byte ^= ((rl & 7) << 4);          // swizzle (read side)
        bf16x8 afrag = *(const bf16x8*)((char*)&tile[0][0] + byte);

        bf16x8 bfrag[8];
#pragma unroll
        for (int nt = 0; nt < 8; ++nt)
            bfrag[nt] = *(const bf16x8*)(WtP + (size_t)((ks * 8 + nt) * 64 + lane) * 8);

#pragma unroll
        for (int nt = 0; nt < 8; ++nt)
            acc[nt] = __builtin_amdgcn_mfma_f32_16x16x32_bf16(afrag, bfrag[nt], acc[nt], 0, 0, 0);
    }

#pragma unroll
    for (int r = 0; r < 4; ++r) {
        int m = R0 + w * 16 + lk * 4 + r;
        if (m < N_NODES) {
#pragma unroll
            for (int nt = 0; nt < 8; ++nt) {
                int n = nt * 16 + l15;
                h[(size_t)m * HID + n] = f2fp8(acc[nt][r]);
            }
        }
    }
}

// ================= kernel 5: fused gather1 + GEMM2 =================
// Block = 16 nodes (3125*16 = 50000). Gather into LDS [16][132] bf16; wave 0
// then computes h2[16][32] = relu(a1) @ W2 via 8 MFMAs (packed Wt2P).

#define ALDS2 132

__global__ __launch_bounds__(256) void k_g1g2(const int* __restrict__ offs,
                                              const int* __restrict__ esrc,
                                              const unsigned char* __restrict__ h,
                                              const float* __restrict__ dinv,
                                              const float* __restrict__ b,
                                              const short* __restrict__ Wt2P,
                                              unsigned char* __restrict__ h2) {
    __shared__ short a_lds[16][ALDS2];
    const int tid = threadIdx.x;
    const int nl = tid >> 4;                 // local node 0..15
    const int node = blockIdx.x * 16 + nl;   // always < N_NODES
    const int lane16 = tid & 15;
    const int f = lane16 * 8;

    float dv = dinv[node];
    uint2 hv = *(const uint2*)(h + (size_t)node * HID + f);
    f32x2 q0 = __builtin_amdgcn_cvt_pk_f32_fp8(hv.x, false);
    f32x2 q1 = __builtin_amdgcn_cvt_pk_f32_fp8(hv.x, true);
    f32x2 q2 = __builtin_amdgcn_cvt_pk_f32_fp8(hv.y, false);
    f32x2 q3 = __builtin_amdgcn_cvt_pk_f32_fp8(hv.y, true);
    float self = dv * dv;
    float a0 = q0[0] * self, a1 = q0[1] * self, a2 = q1[0] * self, a3 = q1[1] * self;
    float a4 = q2[0] * self, a5 = q2[1] * self, a6 = q3[0] * self, a7 = q3[1] * self;

    int beg = offs[node], end = offs[node + 1];
    int p = beg;
#define ACC8(vv, nn) { \
    f32x2 c0 = __builtin_amdgcn_cvt_pk_f32_fp8(vv.x, false); \
    f32x2 c1 = __builtin_amdgcn_cvt_pk_f32_fp8(vv.x, true);  \
    f32x2 c2 = __builtin_amdgcn_cvt_pk_f32_fp8(vv.y, false); \
    f32x2 c3 = __builtin_amdgcn_cvt_pk_f32_fp8(vv.y, true);  \
    a0 += c0[0] * nn; a1 += c0[1] * nn; a2 += c1[0] * nn; a3 += c1[1] * nn; \
    a4 += c2[0] * nn; a5 += c2[1] * nn; a6 += c3[0] * nn; a7 += c3[1] * nn; }
    for (; p + 7 < end; p += 8) {
        int s0 = esrc[p + 0], s1 = esrc[p + 1], s2 = esrc[p + 2], s3 = esrc[p + 3];
        int s4 = esrc[p + 4], s5 = esrc[p + 5], s6 = esrc[p + 6], s7 = esrc[p + 7];
        float n0 = dinv[s0] * dv, n1 = dinv[s1] * dv, n2 = dinv[s2] * dv, n3 = dinv[s3] * dv;
        float n4 = dinv[s4] * dv, n5 = dinv[s5] * dv, n6 = dinv[s6] * dv, n7 = dinv[s7] * dv;
        uint2 v0 = *(const uint2*)(h + (size_t)s0 * HID + f);
        uint2 v1 = *(const uint2*)(h + (size_t)s1 * HID + f);
        uint2 v2 = *(const uint2*)(h + (size_t)s2 * HID + f);
        uint2 v3 = *(const uint2*)(h + (size_t)s3 * HID + f);
        uint2 v4 = *(const uint2*)(h + (size_t)s4 * HID + f);
        uint2 v5 = *(const uint2*)(h + (size_t)s5 * HID + f);
        uint2 v6 = *(const uint2*)(h + (size_t)s6 * HID + f);
        uint2 v7 = *(const uint2*)(h + (size_t)s7 * HID + f);
        ACC8(v0, n0); ACC8(v1, n1); ACC8(v2, n2); ACC8(v3, n3);
        ACC8(v4, n4); ACC8(v5, n5); ACC8(v6, n6); ACC8(v7, n7);
    }
    for (; p + 3 < end; p += 4) {
        int s0 = esrc[p + 0], s1 = esrc[p + 1], s2 = esrc[p + 2], s3 = esrc[p + 3];
        float n0 = dinv[s0] * dv, n1 = dinv[s1] * dv, n2 = dinv[s2] * dv, n3 = dinv[s3] * dv;
        uint2 v0 = *(const uint2*)(h + (size_t)s0 * HID + f);
        uint2 v1 = *(const uint2*)(h + (size_t)s1 * HID + f);
        uint2 v2 = *(const uint2*)(h + (size_t)s2 * HID + f);
        uint2 v3 = *(const uint2*)(h + (size_t)s3 * HID + f);
        ACC8(v0, n0); ACC8(v1, n1); ACC8(v2, n2); ACC8(v3, n3);
    }
    for (; p < end; ++p) {
        int s = esrc[p];
        float nrm = dinv[s] * dv;
        uint2 v = *(const uint2*)(h + (size_t)s * HID + f);
        ACC8(v, nrm);
    }
#undef ACC8
    float4 bv0 = *(const float4*)(b + f);
    float4 bv1 = *(const float4*)(b + f + 4);
    s16x8 o = { f2bf(a0 + bv0.x), f2bf(a1 + bv0.y), f2bf(a2 + bv0.z), f2bf(a3 + bv0.w),
                f2bf(a4 + bv1.x), f2bf(a5 + bv1.y), f2bf(a6 + bv1.z), f2bf(a7 + bv1.w) };
    *(s16x8*)&a_lds[nl][f] = o;
    __syncthreads();

    // ---- GEMM2 tail on wave 0 ----
    if (tid < 64) {
        const int lane = tid;
        const int l15 = lane & 15;
        const int lk  = lane >> 4;
        f32x4 acc[2] = {};
#pragma unroll
        for (int ks = 0; ks < HID / 32; ++ks) {
            const int kbase = ks * 32 + lk * 8;
            bf16x8 av = *(const bf16x8*)&a_lds[l15][kbase];
#pragma unroll
            for (int e = 0; e < 8; ++e) if (av[e] < 0) av[e] = 0;   // bf16 relu
#pragma unroll
            for (int nt = 0; nt < 2; ++nt) {
                bf16x8 bfrag = *(const bf16x8*)(Wt2P + (size_t)((ks * 2 + nt) * 64 + lane) * 8);
                acc[nt] = __builtin_amdgcn_mfma_f32_16x16x32_bf16(av, bfrag, acc[nt], 0, 0, 0);
            }
        }
#pragma unroll
        for (int r = 0; r < 4; ++r) {
            int m = blockIdx.x * 16 + lk * 4 + r;
#pragma unroll
            for (int nt = 0; nt < 2; ++nt) {
                int n = nt * 16 + l15;
                h2[(size_t)m * CLS + n] = f2fp8(acc[nt][r]);
            }
        }
    }
}

// ================= kernel 6: gather2 (fp8 in) + bias + log-softmax =================

__global__ __launch_bounds__(256) void k_gather2(const int* __restrict__ offs,
                                                 const int* __restrict__ esrc,
                                                 const unsigned char* __restrict__ h,
                                                 const float* __restrict__ dinv,
                                                 const float* __restrict__ b,
                                                 float* __restrict__ out) {
    int node = blockIdx.x * 32 + (threadIdx.x >> 3);
    int sub = threadIdx.x & 7;
    if (node >= N_NODES) return;
    int f = sub * 4;
    float dv = dinv[node];
    unsigned hv = *(const unsigned*)(h + (size_t)node * CLS + f);
    f32x2 hlo = __builtin_amdgcn_cvt_pk_f32_fp8(hv, false);
    f32x2 hhi = __builtin_amdgcn_cvt_pk_f32_fp8(hv, true);
    float self = dv * dv;
    float a0 = hlo[0] * self, a1 = hlo[1] * self, a2 = hhi[0] * self, a3 = hhi[1] * self;
    int beg = offs[node], end = offs[node + 1];
    int p = beg;
#define ACC4(vv, nn) { \
    f32x2 l = __builtin_amdgcn_cvt_pk_f32_fp8(vv, false); \
    f32x2 u = __builtin_amdgcn_cvt_pk_f32_fp8(vv, true);  \
    a0 += l[0] * nn; a1 += l[1] * nn; a2 += u[0] * nn; a3 += u[1] * nn; }
    for (; p + 7 < end; p += 8) {
        int s0 = esrc[p], s1 = esrc[p + 1], s2 = esrc[p + 2], s3 = esrc[p + 3];
        int s4 = esrc[p + 4], s5 = esrc[p + 5], s6 = esrc[p + 6], s7 = esrc[p + 7];
        float n0 = dinv[s0] * dv, n1 = dinv[s1] * dv, n2 = dinv[s2] * dv, n3 = dinv[s3] * dv;
        float n4 = dinv[s4] * dv, n5 = dinv[s5] * dv, n6 = dinv[s6] * dv, n7 = dinv[s7] * dv;
        unsigned v0 = *(const unsigned*)(h + (size_t)s0 * CLS + f);
        unsigned v1 = *(const unsigned*)(h + (size_t)s1 * CLS + f);
        unsigned v2 = *(const unsigned*)(h + (size_t)s2 * CLS + f);
        unsigned v3 = *(const unsigned*)(h + (size_t)s3 * CLS + f);
        unsigned v4 = *(const unsigned*)(h + (size_t)s4 * CLS + f);
        unsigned v5 = *(const unsigned*)(h + (size_t)s5 * CLS + f);
        unsigned v6 = *(const unsigned*)(h + (size_t)s6 * CLS + f);
        unsigned v7 = *(const unsigned*)(h + (size_t)s7 * CLS + f);
        ACC4(v0, n0); ACC4(v1, n1); ACC4(v2, n2); ACC4(v3, n3);
        ACC4(v4, n4); ACC4(v5, n5); ACC4(v6, n6); ACC4(v7, n7);
    }
    for (; p + 3 < end; p += 4) {
        int s0 = esrc[p], s1 = esrc[p + 1], s2 = esrc[p + 2], s3 = esrc[p + 3];
        float n0 = dinv[s0] * dv, n1 = dinv[s1] * dv, n2 = dinv[s2] * dv, n3 = dinv[s3] * dv;
        unsigned v0 = *(const unsigned*)(h + (size_t)s0 * CLS + f);
        unsigned v1 = *(const unsigned*)(h + (size_t)s1 * CLS + f);
        unsigned v2 = *(const unsigned*)(h + (size_t)s2 * CLS + f);
        unsigned v3 = *(const unsigned*)(h + (size_t)s3 * CLS + f);
        ACC4(v0, n0); ACC4(v1, n1); ACC4(v2, n2); ACC4(v3, n3);
    }
    for (; p < end; ++p) {
        int s = esrc[p];
        float nrm = dinv[s] * dv;
        unsigned v = *(const unsigned*)(h + (size_t)s * CLS + f);
        ACC4(v, nrm);
    }
#undef ACC4
    float4 bv = *(const float4*)(b + f);
    float4 acc = { a0 + bv.x, a1 + bv.y, a2 + bv.z, a3 + bv.w };

    float m = fmaxf(fmaxf(acc.x, acc.y), fmaxf(acc.z, acc.w));
    m = fmaxf(m, __shfl_xor(m, 1, 8));
    m = fmaxf(m, __shfl_xor(m, 2, 8));
    m = fmaxf(m, __shfl_xor(m, 4, 8));
    float sum = expf(acc.x - m) + expf(acc.y - m) + expf(acc.z - m) + expf(acc.w - m);
    sum += __shfl_xor(sum, 1, 8);
    sum += __shfl_xor(sum, 2, 8);
    sum += __shfl_xor(sum, 4, 8);
    float l = m + logf(sum);
    float4 o = { acc.x - l, acc.y - l, acc.z - l, acc.w - l };
    *(float4*)(out + (size_t)node * CLS + f) = o;
}

// ================= launch =================

extern "C" void kernel_launch(void* const* d_in, const int* in_sizes, int n_in,
                              void* d_out, int out_size, void* d_ws, size_t ws_size,
                              hipStream_t stream) {
    const float* x  = (const float*)d_in[0];
    const int*   ei = (const int*)d_in[1];
    const float* W1 = (const float*)d_in[2];
    const float* b1 = (const float*)d_in[3];
    const float* W2 = (const float*)d_in[4];
    const float* b2 = (const float*)d_in[5];
    float* out = (float*)d_out;

    const int* src = ei;
    const int* dst = ei + N_EDGE;

    int* counts   = (int*)d_ws;                           // NB*NPART
    int* base     = counts + NB * NPART;                  // NB*NPART
    int* ptot     = base + NB * NPART;                    // 256
    int* bucket   = ptot + 256;                           // N_EDGE
    int* offs     = bucket + N_EDGE;                      // N_PAD
    int* esrc     = offs + N_PAD;                         // N_EDGE
    float* dinv   = (float*)(esrc + N_EDGE);              // N_PAD
    unsigned char* h1 = (unsigned char*)(dinv + N_PAD);   // N*HID fp8
    unsigned char* h2 = h1 + (size_t)N_NODES * HID;       // N*CLS fp8
    short* WtP    = (short*)(h2 + (size_t)N_NODES * CLS); // 32768 bf16 packed
    short* Wt2P   = WtP + HID * F_IN;                     // 4096 bf16 packed

    k_pre       <<<NB + 128 + 16, 256, 0, stream>>>(dst, counts, W1, WtP, W2, Wt2P);
    k_scanP1    <<<NPART,         256, 0, stream>>>(counts, base, ptot);
    k_bucket    <<<NB,            256, 0, stream>>>(src, dst, base, ptot, bucket);
    k_csrf_gemm1<<<NPART + GBLKS, 256, 0, stream>>>(bucket, ptot, esrc, offs, dinv, x, WtP, h1);

    k_g1g2      <<<3125,          256, 0, stream>>>(offs, esrc, h1, dinv, b1, Wt2P, h2);
    k_gather2   <<<1563,          256, 0, stream>>>(offs, esrc, h2, dinv, b2, out);
}